// Round 1
// baseline (712.870 us; speedup 1.0000x reference)
//
#include <hip/hip_runtime.h>
#include <math.h>

#define NB 16
#define NH 1024
#define NT 4096
#define CD 8
#define CS 1024
#define NBT (NB*NT)

// ---------------- K0: prepare fp64 tables in workspace ----------------
__global__ __launch_bounds__(256) void k0_prep(
    const float* __restrict__ w,      // in_proj_w [CD][NH]
    const float* __restrict__ bias,   // in_proj_b [CD]
    const float* __restrict__ cb,     // codebook [CS][CD]
    double* __restrict__ Wt,          // out: [NH][CD]
    double* __restrict__ biasd,       // out: [CD]
    double* __restrict__ cbn,         // out: normalized codebook [CS][CD]
    double* __restrict__ cbn2,        // out: sum(cbn^2) per code [CS]
    double* __restrict__ lossacc)     // out: zeroed accumulator
{
    int g = blockIdx.x * 256 + threadIdx.x;   // grid = 32*256 = 8192
    if (g < CD * NH) {
        int h = g >> 3, d = g & 7;
        Wt[g] = (double)w[d * NH + h];
    }
    if (g < CS) {
        double v[CD];
        double s = 0.0;
        #pragma unroll
        for (int j = 0; j < CD; j++) { v[j] = (double)cb[g * CD + j]; s += v[j] * v[j]; }
        double n = sqrt(s);
        double m = fmax(n, 1e-12);
        double s2 = 0.0;
        #pragma unroll
        for (int j = 0; j < CD; j++) {
            double q = v[j] / m;          // replicate x / max(n,eps) exactly
            cbn[g * CD + j] = q;
            s2 += q * q;
        }
        cbn2[g] = s2;
    }
    if (g < CD) biasd[g] = (double)bias[g];
    if (g == 0) *lossacc = 0.0;
}

// ---------------- K1: proj[b,d,t] = sum_h x[b,h,t]*W[d,h] + bias (fp64) ----------------
__global__ __launch_bounds__(256) void k1_proj(
    const float*  __restrict__ x,      // hidden [NB][NH][NT]
    const double* __restrict__ Wt,     // [NH][CD]
    const double* __restrict__ biasd,  // [CD]
    double* __restrict__ projd,        // out: [NBT][CD] fp64
    float*  __restrict__ projf)        // out: d_out proj region [NB][CD][NT] fp32
{
    __shared__ double red[4][64][CD];  // 16 KB
    const int tx = threadIdx.x;        // 64 lanes over t
    const int ty = threadIdx.y;        // 4 h-chunks
    const int bt = blockIdx.x * 64 + tx;
    const int b  = bt >> 12;           // NT = 4096
    const int t  = bt & (NT - 1);
    const float* xp = x + ((size_t)b * NH) * NT + t;
    // ty is wave-uniform because blockDim.x == 64; make the compiler see it.
    const int h0 = __builtin_amdgcn_readfirstlane(ty * 256);

    double acc[CD];
    #pragma unroll
    for (int d = 0; d < CD; d++) acc[d] = 0.0;

    #pragma unroll 4
    for (int i = 0; i < 256; i++) {
        const int h = h0 + i;
        const double xv = (double)xp[(size_t)h * NT];
        const double* wr = Wt + h * CD;   // wave-uniform address -> scalar loads
        #pragma unroll
        for (int d = 0; d < CD; d++) acc[d] = fma(xv, wr[d], acc[d]);
    }

    #pragma unroll
    for (int d = 0; d < CD; d++) red[ty][tx][d] = acc[d];
    __syncthreads();

    if (ty == 0) {
        #pragma unroll
        for (int d = 0; d < CD; d++) {
            double s = red[0][tx][d];
            s += red[1][tx][d];
            s += red[2][tx][d];
            s += red[3][tx][d];
            s += biasd[d];
            projd[(size_t)bt * CD + d] = s;
            projf[((size_t)b * CD + d) * NT + t] = (float)s;
        }
    }
}

// ---------------- K2: cosine-NN argmax + loss partial sums ----------------
__global__ __launch_bounds__(256) void k2_argmax(
    const double* __restrict__ projd,  // [NBT][CD]
    const double* __restrict__ cbn,    // [CS][CD]
    const double* __restrict__ cbn2,   // [CS]
    const float*  __restrict__ cb,     // codebook fp32 [CS][CD]
    float* __restrict__ idxf,          // d_out indices region (as float)
    int*   __restrict__ idxi,          // ws int indices
    double* __restrict__ lossacc)
{
    const int bt = blockIdx.x * 256 + threadIdx.x;

    double p[CD];
    #pragma unroll
    for (int d = 0; d < CD; d++) p[d] = projd[(size_t)bt * CD + d];

    double s = 0.0;
    #pragma unroll
    for (int d = 0; d < CD; d++) s += p[d] * p[d];
    const double n = sqrt(s);
    const double m = fmax(n, 1e-12);
    double pn[CD];
    #pragma unroll
    for (int d = 0; d < CD; d++) pn[d] = p[d] / m;   // replicate x / max(n,eps)
    double l2 = 0.0;
    #pragma unroll
    for (int d = 0; d < CD; d++) l2 += pn[d] * pn[d];

    double best = -1e300;
    int bi = 0;
    for (int c = 0; c < CS; c++) {
        const double* cr = cbn + c * CD;   // uniform address -> scalar loads
        double dot = 0.0;
        #pragma unroll
        for (int d = 0; d < CD; d++) dot = fma(pn[d], cr[d], dot);
        const double dist = -(l2 - 2.0 * dot) + cbn2[c];
        if (dist > best) { best = dist; bi = c; }   // strict > keeps first max (np.argmax)
    }

    idxf[bt] = (float)bi;
    idxi[bt] = bi;

    // loss: mean((proj_f32 - quant_f32)^2); commitment == codebook value in fwd
    const float* qr = cb + bi * CD;
    double ls = 0.0;
    #pragma unroll
    for (int d = 0; d < CD; d++) {
        const float pf = (float)p[d];
        const float df = pf - qr[d];
        const float sq = df * df;
        ls += (double)sq;
    }
    #pragma unroll
    for (int o = 32; o > 0; o >>= 1) ls += __shfl_down(ls, o, 64);
    if ((threadIdx.x & 63) == 0) atomicAdd(lossacc, ls);
}

// ---------------- K4: out[b,h,t] = sum_d q_st[d]*Wout[h,d] + bout[h] ----------------
__global__ __launch_bounds__(256) void k4_out(
    const double* __restrict__ projd,  // [NBT][CD]
    const int*    __restrict__ idxi,   // [NBT]
    const float*  __restrict__ cb,     // [CS][CD]
    const float*  __restrict__ wo,     // out_proj_w [NH][CD]
    const float*  __restrict__ bo,     // out_proj_b [NH]
    const double* __restrict__ lossacc,
    float* __restrict__ out,           // [NB][NH][NT]
    float* __restrict__ lossout)       // 2 floats
{
    if (blockIdx.x == 0 && threadIdx.x == 0 && threadIdx.y == 0) {
        const float v = (float)(*lossacc / (double)(NB * CD * NT));
        lossout[0] = v;   // commitment_loss
        lossout[1] = v;   // codebook_loss (identical forward value)
    }

    const int tx = threadIdx.x;
    const int ty = threadIdx.y;
    const int bt = blockIdx.x * 64 + tx;
    const int b  = bt >> 12;
    const int t  = bt & (NT - 1);

    const int bi = idxi[bt];
    float q[CD];
    #pragma unroll
    for (int d = 0; d < CD; d++) {
        const float pf = (float)projd[(size_t)bt * CD + d];
        const float cf = cb[bi * CD + d];
        q[d] = pf + (cf - pf);   // straight-through forward value (replicated rounding)
    }

    const int h0 = __builtin_amdgcn_readfirstlane(ty * 256);
    float* op = out + ((size_t)b * NH) * NT + t;

    #pragma unroll 4
    for (int i = 0; i < 256; i++) {
        const int h = h0 + i;
        const float* wr = wo + h * CD;   // uniform address -> scalar loads
        float o = 0.f;
        #pragma unroll
        for (int d = 0; d < CD; d++) o = fmaf(q[d], wr[d], o);
        o += bo[h];
        op[(size_t)h * NT] = o;
    }
}

// ---------------- launch ----------------
extern "C" void kernel_launch(void* const* d_in, const int* in_sizes, int n_in,
                              void* d_out, int out_size, void* d_ws, size_t ws_size,
                              hipStream_t stream) {
    const float* hidden = (const float*)d_in[0];
    const float* ipw    = (const float*)d_in[1];
    const float* ipb    = (const float*)d_in[2];
    const float* opw    = (const float*)d_in[3];
    const float* opb    = (const float*)d_in[4];
    const float* cb     = (const float*)d_in[5];

    float* out      = (float*)d_out;                    // [NB][NH][NT]
    float* loss_out = out + (size_t)NB * NH * NT;       // 2 scalars
    float* idxf     = loss_out + 2;                     // [NB*NT]
    float* projf    = idxf + NBT;                       // [NB][CD][NT]

    double* Wt      = (double*)d_ws;                    // 8192
    double* biasd   = Wt + CD * NH;                     // 8
    double* cbn     = biasd + 8;                        // 8192 (64B aligned)
    double* cbn2    = cbn + (size_t)CS * CD;            // 1024
    double* lossacc = cbn2 + CS;                        // 1 (+7 pad)
    double* projd   = lossacc + 8;                      // NBT*CD doubles (64B aligned)
    int*    idxi    = (int*)(projd + (size_t)NBT * CD); // NBT ints
    // total ws use ~4.6 MB

    k0_prep<<<32, 256, 0, stream>>>(ipw, ipb, cb, Wt, biasd, cbn, cbn2, lossacc);
    k1_proj<<<NBT / 64, dim3(64, 4), 0, stream>>>(hidden, Wt, biasd, projd, projf);
    k2_argmax<<<NBT / 256, 256, 0, stream>>>(projd, cbn, cbn2, cb, idxf, idxi, lossacc);
    k4_out<<<NBT / 64, dim3(64, 4), 0, stream>>>(projd, idxi, cb, opw, opb, lossacc, out, loss_out);
}

// Round 2
// 544.052 us; speedup vs baseline: 1.3103x; 1.3103x over previous
//
#include <hip/hip_runtime.h>
#include <math.h>

#define NB 16
#define NH 1024
#define NT 4096
#define CD 8
#define CS 1024
#define NBT (NB*NT)

// ---------------- K0: prepare fp64 tables in workspace ----------------
__global__ __launch_bounds__(256) void k0_prep(
    const float* __restrict__ w,      // in_proj_w [CD][NH]
    const float* __restrict__ bias,   // in_proj_b [CD]
    const float* __restrict__ cb,     // codebook [CS][CD]
    double* __restrict__ Wt,          // out: [NH][CD]
    double* __restrict__ biasd,       // out: [CD]
    double* __restrict__ cbn,         // out: normalized codebook [CS][CD]
    double* __restrict__ cbn2,        // out: sum(cbn^2) per code [CS]
    double* __restrict__ lossacc)     // out: zeroed accumulator
{
    int g = blockIdx.x * 256 + threadIdx.x;   // grid = 32*256 = 8192
    if (g < CD * NH) {
        int h = g >> 3, d = g & 7;
        Wt[g] = (double)w[d * NH + h];
    }
    if (g < CS) {
        double v[CD];
        double s = 0.0;
        #pragma unroll
        for (int j = 0; j < CD; j++) { v[j] = (double)cb[g * CD + j]; s += v[j] * v[j]; }
        double n = sqrt(s);
        double m = fmax(n, 1e-12);
        double s2 = 0.0;
        #pragma unroll
        for (int j = 0; j < CD; j++) {
            double q = v[j] / m;          // replicate x / max(n,eps) exactly
            cbn[g * CD + j] = q;
            s2 += q * q;
        }
        cbn2[g] = s2;
    }
    if (g < CD) biasd[g] = (double)bias[g];
    if (g == 0) *lossacc = 0.0;
}

// ---------------- K1: proj[b,d,t] = sum_h x[b,h,t]*W[d,h] + bias (fp64) ----------------
// block (64,8): lanes = 64 consecutive t, ty = 128-h chunk. 1024 blocks -> 32 waves/CU.
__global__ __launch_bounds__(512) void k1_proj(
    const float*  __restrict__ x,      // hidden [NB][NH][NT]
    const double* __restrict__ Wt,     // [NH][CD]
    const double* __restrict__ biasd,  // [CD]
    double* __restrict__ projd,        // out: [NBT][CD] fp64
    float*  __restrict__ projf)        // out: d_out proj region [NB][CD][NT] fp32
{
    __shared__ double red[CD][8][64];  // 32 KB, lane-consecutive -> conflict-free
    const int tx = threadIdx.x;
    const int ty = threadIdx.y;
    const int bt = blockIdx.x * 64 + tx;
    const int b  = bt >> 12;           // NT = 4096
    const int t  = bt & (NT - 1);
    const float* xp = x + ((size_t)b * NH) * NT + t;
    const int h0 = __builtin_amdgcn_readfirstlane(ty * 128);

    double acc[CD];
    #pragma unroll
    for (int d = 0; d < CD; d++) acc[d] = 0.0;

    for (int i = 0; i < 128; i += 16) {
        float xv[16];
        #pragma unroll
        for (int j = 0; j < 16; j++) xv[j] = xp[(size_t)(h0 + i + j) * NT];
        #pragma unroll
        for (int j = 0; j < 16; j++) {
            const double xd = (double)xv[j];
            const double* wr = Wt + (h0 + i + j) * CD;  // wave-uniform -> scalar loads
            #pragma unroll
            for (int d = 0; d < CD; d++) acc[d] = fma(xd, wr[d], acc[d]);
        }
    }

    #pragma unroll
    for (int d = 0; d < CD; d++) red[d][ty][tx] = acc[d];
    __syncthreads();

    if (ty == 0) {
        #pragma unroll
        for (int d = 0; d < CD; d++) {
            double s = 0.0;
            #pragma unroll
            for (int j = 0; j < 8; j++) s += red[d][j][tx];
            s += biasd[d];
            projd[(size_t)bt * CD + d] = s;
            projf[((size_t)b * CD + d) * NT + t] = (float)s;
        }
    }
}

// ---------------- K2: cosine-NN argmax + loss partial sums ----------------
// block (64,8): lanes = 64 rows, ty = 128-code chunk. 1024 blocks -> 32 waves/CU.
__global__ __launch_bounds__(512) void k2_argmax(
    const double* __restrict__ projd,  // [NBT][CD]
    const double* __restrict__ cbn,    // [CS][CD]
    const double* __restrict__ cbn2,   // [CS]
    const float*  __restrict__ cb,     // codebook fp32 [CS][CD]
    float* __restrict__ idxf,          // d_out indices region (as float)
    int*   __restrict__ idxi,          // ws int indices
    double* __restrict__ lossacc)
{
    __shared__ double bestv_s[8][64];
    __shared__ int    besti_s[8][64];
    const int tx = threadIdx.x;
    const int ty = threadIdx.y;
    const int bt = blockIdx.x * 64 + tx;

    double p[CD];
    #pragma unroll
    for (int d = 0; d < CD; d++) p[d] = projd[(size_t)bt * CD + d];

    double s = 0.0;
    #pragma unroll
    for (int d = 0; d < CD; d++) s += p[d] * p[d];
    const double m = fmax(sqrt(s), 1e-12);
    // dist = -(l2 - 2*dot) + cbn2[c]; -l2 is a per-row constant -> drop for argmax.
    // fold 2/m into the query: dist' = cbn2[c] + sum_d (2*p[d]/m) * cbn[c][d]
    double pn2[CD];
    #pragma unroll
    for (int d = 0; d < CD; d++) pn2[d] = 2.0 * (p[d] / m);

    const int c0 = __builtin_amdgcn_readfirstlane(ty * 128);
    double best = -1e300;
    int bi = 0;
    #pragma unroll 4
    for (int c = 0; c < 128; c++) {
        const double* cr = cbn + (size_t)(c0 + c) * CD;  // wave-uniform -> scalar loads
        double dot = cbn2[c0 + c];
        #pragma unroll
        for (int d = 0; d < CD; d++) dot = fma(pn2[d], cr[d], dot);
        if (dot > best) { best = dot; bi = c; }   // strict > keeps first max
    }
    bestv_s[ty][tx] = best;
    besti_s[ty][tx] = c0 + bi;
    __syncthreads();

    if (ty == 0) {
        double bv = bestv_s[0][tx];
        int    bc = besti_s[0][tx];
        #pragma unroll
        for (int j = 1; j < 8; j++) {
            const double v = bestv_s[j][tx];
            const int    c = besti_s[j][tx];
            if (v > bv) { bv = v; bc = c; }       // ties keep earlier chunk (np.argmax)
        }
        idxf[bt] = (float)bc;
        idxi[bt] = bc;

        // loss: mean((proj_f32 - quant_f32)^2)
        const float* qr = cb + (size_t)bc * CD;
        double ls = 0.0;
        #pragma unroll
        for (int d = 0; d < CD; d++) {
            const float pf = (float)p[d];
            const float df = pf - qr[d];
            const float sq = df * df;
            ls += (double)sq;
        }
        #pragma unroll
        for (int o = 32; o > 0; o >>= 1) ls += __shfl_down(ls, o, 64);
        if (tx == 0) atomicAdd(lossacc, ls);
    }
}

// ---------------- K4: out[b,h,t] = sum_d q_st[d]*Wout[h,d] + bout[h] ----------------
// block (64,8): lanes = 64 consecutive t, ty = 128-h chunk. 1024 blocks.
__global__ __launch_bounds__(512) void k4_out(
    const double* __restrict__ projd,  // [NBT][CD]
    const int*    __restrict__ idxi,   // [NBT]
    const float*  __restrict__ cb,     // [CS][CD]
    const float*  __restrict__ wo,     // out_proj_w [NH][CD]
    const float*  __restrict__ bo,     // out_proj_b [NH]
    const double* __restrict__ lossacc,
    float* __restrict__ out,           // [NB][NH][NT]
    float* __restrict__ lossout)       // 2 floats
{
    if (blockIdx.x == 0 && threadIdx.x == 0 && threadIdx.y == 0) {
        const float v = (float)(*lossacc / (double)(NB * CD * NT));
        lossout[0] = v;   // commitment_loss
        lossout[1] = v;   // codebook_loss (identical forward value)
    }

    const int tx = threadIdx.x;
    const int ty = threadIdx.y;
    const int bt = blockIdx.x * 64 + tx;
    const int b  = bt >> 12;
    const int t  = bt & (NT - 1);

    const int bi = idxi[bt];
    float q[CD];
    #pragma unroll
    for (int d = 0; d < CD; d++) {
        const float pf = (float)projd[(size_t)bt * CD + d];
        const float cf = cb[(size_t)bi * CD + d];
        q[d] = pf + (cf - pf);   // straight-through forward value (replicated rounding)
    }

    const int h0 = __builtin_amdgcn_readfirstlane(ty * 128);
    float* op = out + ((size_t)b * NH) * NT + t;

    #pragma unroll 4
    for (int i = 0; i < 128; i++) {
        const int h = h0 + i;
        const float* wr = wo + (size_t)h * CD;   // wave-uniform -> scalar loads
        float o = 0.f;
        #pragma unroll
        for (int d = 0; d < CD; d++) o = fmaf(q[d], wr[d], o);
        o += bo[h];
        op[(size_t)h * NT] = o;
    }
}

// ---------------- launch ----------------
extern "C" void kernel_launch(void* const* d_in, const int* in_sizes, int n_in,
                              void* d_out, int out_size, void* d_ws, size_t ws_size,
                              hipStream_t stream) {
    const float* hidden = (const float*)d_in[0];
    const float* ipw    = (const float*)d_in[1];
    const float* ipb    = (const float*)d_in[2];
    const float* opw    = (const float*)d_in[3];
    const float* opb    = (const float*)d_in[4];
    const float* cb     = (const float*)d_in[5];

    float* out      = (float*)d_out;                    // [NB][NH][NT]
    float* loss_out = out + (size_t)NB * NH * NT;       // 2 scalars
    float* idxf     = loss_out + 2;                     // [NB*NT]
    float* projf    = idxf + NBT;                       // [NB][CD][NT]

    double* Wt      = (double*)d_ws;                    // 8192
    double* biasd   = Wt + CD * NH;                     // 8
    double* cbn     = biasd + 8;                        // 8192 (64B aligned)
    double* cbn2    = cbn + (size_t)CS * CD;            // 1024
    double* lossacc = cbn2 + CS;                        // 1 (+7 pad)
    double* projd   = lossacc + 8;                      // NBT*CD doubles (64B aligned)
    int*    idxi    = (int*)(projd + (size_t)NBT * CD); // NBT ints

    k0_prep<<<32, 256, 0, stream>>>(ipw, ipb, cb, Wt, biasd, cbn, cbn2, lossacc);
    k1_proj<<<NBT / 64, dim3(64, 8), 0, stream>>>(hidden, Wt, biasd, projd, projf);
    k2_argmax<<<NBT / 64, dim3(64, 8), 0, stream>>>(projd, cbn, cbn2, cb, idxf, idxi, lossacc);
    k4_out<<<NBT / 64, dim3(64, 8), 0, stream>>>(projd, idxi, cb, opw, opb, lossacc, out, loss_out);
}